// Round 7
// baseline (1158.763 us; speedup 1.0000x reference)
//
#include <hip/hip_runtime.h>

typedef unsigned int uint;
typedef unsigned short ushort;

#define D 512

typedef __attribute__((ext_vector_type(8))) short bf16x8;
typedef __attribute__((ext_vector_type(4))) float f32x4;

__device__ __forceinline__ ushort f2b(float f) {
  uint u = __builtin_bit_cast(uint, f);
  return (ushort)((u + 0x7FFFu + ((u >> 16) & 1u)) >> 16);  // RNE
}
__device__ __forceinline__ float b_lo(uint u) { return __builtin_bit_cast(float, u << 16); }
__device__ __forceinline__ float b_hi(uint u) { return __builtin_bit_cast(float, u & 0xFFFF0000u); }

// ---------------- f32 -> bf16 bulk convert (8 elems/thread) ----------------
__global__ __launch_bounds__(256) void f32_to_bf16_vec(const float* __restrict__ in,
                                                       ushort* __restrict__ out, int n8) {
  const int i = blockIdx.x * 256 + threadIdx.x;
  if (i >= n8) return;
  const float4* p = (const float4*)in + (size_t)i * 2;
  float4 a = p[0], b = p[1];
  uint4 o;
  o.x = f2b(a.x) | ((uint)f2b(a.y) << 16);
  o.y = f2b(a.z) | ((uint)f2b(a.w) << 16);
  o.z = f2b(b.x) | ((uint)f2b(b.y) << 16);
  o.w = f2b(b.z) | ((uint)f2b(b.w) << 16);
  ((uint4*)out)[i] = o;
}

// ------------- transpose 512x512 f32 [k][o] -> bf16 BT [o][k] --------------
__global__ __launch_bounds__(256) void transpose_bf16(const float* __restrict__ W,
                                                      ushort* __restrict__ BT) {
  __shared__ float tile[64][65];
  const int bk = blockIdx.x * 64;  // k block
  const int bo = blockIdx.y * 64;  // o block
  const int tx = threadIdx.x & 63, ty = threadIdx.x >> 6;
#pragma unroll
  for (int r = 0; r < 64; r += 4)
    tile[r + ty][tx] = W[(size_t)(bk + r + ty) * D + bo + tx];
  __syncthreads();
#pragma unroll
  for (int r = 0; r < 64; r += 4)
    BT[(size_t)(bo + r + ty) * D + bk + tx] = f2b(tile[tx][r + ty]);
}

// ---------------------------- CSR build ------------------------------------
__global__ void count_deg(const int* __restrict__ dst, int* __restrict__ deg, int E) {
  const int e = blockIdx.x * 256 + threadIdx.x;
  if (e < E) atomicAdd(&deg[dst[e]], 1);
}

__global__ __launch_bounds__(256) void scan_block(const int* __restrict__ in,
                                                  int* __restrict__ out,
                                                  int* __restrict__ bsum) {
  __shared__ int sm[256];
  const int t = threadIdx.x;
  const int gi = blockIdx.x * 256 + t;
  const int v = in[gi];
  int x = v;
  sm[t] = x;
  __syncthreads();
#pragma unroll
  for (int off = 1; off < 256; off <<= 1) {
    const int y = (t >= off) ? sm[t - off] : 0;
    __syncthreads();
    x += y;
    sm[t] = x;
    __syncthreads();
  }
  out[gi] = x - v;  // exclusive
  if (t == 255 && bsum) bsum[blockIdx.x] = x;
}

__global__ void scan_fixup(int* __restrict__ rowptr, const int* __restrict__ bsum,
                           int* __restrict__ cursor, int N, int E) {
  const int i = blockIdx.x * 256 + threadIdx.x;
  const int r = rowptr[i] + bsum[i >> 8];
  rowptr[i] = r;
  cursor[i] = r;
  if (i == 0) rowptr[N] = E;
}

__global__ void fill_csr(const int* __restrict__ src, const int* __restrict__ dst,
                         int* __restrict__ cursor, int* __restrict__ csr, int E) {
  const int e = blockIdx.x * 256 + threadIdx.x;
  if (e >= E) return;
  const int pos = atomicAdd(&cursor[dst[e]], 1);
  csr[pos] = src[e];
}

// ------------------- graph start offsets (batch is sorted) -----------------
__global__ void compute_gstart(const int* __restrict__ batch, int* __restrict__ gstart,
                               int N, int B) {
  const int n = blockIdx.x * 256 + threadIdx.x;
  if (n >= N) return;
  const int b = batch[n];
  const int bp = (n == 0) ? -1 : batch[n - 1];
  for (int x = bp + 1; x <= b; ++x) gstart[x] = n;
  if (n == N - 1)
    for (int x = b + 1; x <= B; ++x) gstart[x] = N;
}

#define ACC8(v)                                          \
  a[0] += b_lo((v).x); a[1] += b_hi((v).x);              \
  a[2] += b_lo((v).y); a[3] += b_hi((v).y);              \
  a[4] += b_lo((v).z); a[5] += b_hi((v).z);              \
  a[6] += b_lo((v).w); a[7] += b_hi((v).w)

// ================== fused GIN layer: agg + MLP(2 GEMMs) ====================
// Block = 64 nodes, 512 threads (8 waves). Phases:
//  A: wave w aggregates rows w*8..w*8+7 -> hT[64][512] bf16 in LDS (swizzled:
//     data chunk l (16B) of row r stored at LDS chunk (l&56)|((l&7)^(r&7))).
//  B: t = leaky(h @ W1 + b1); A-frags from hT, B-frags straight from L2
//     (W1T is 0.5MB, L2-resident, read by every block on the XCD).
//     Wave w owns output cols w*64..w*64+63 -> acc 16 x f32x4.
//     Then scatter t back into hT (barrier both sides).
//  C: x' = leaky(t @ W2 + b2), same structure; scatter into hT; coalesced
//     1KB-row store to xout (+f32 for the last layer).
// hb/tb HBM round-trips eliminated; gather latency overlaps MFMA.
__global__ __launch_bounds__(512) void gin_layer(
    const ushort* __restrict__ xin, const int* __restrict__ rowptr,
    const int* __restrict__ csr, const float* __restrict__ eps_arr, int layer,
    const ushort* __restrict__ W1T, const float* __restrict__ b1,
    const ushort* __restrict__ W2T, const float* __restrict__ b2,
    ushort* __restrict__ xoutb, float* __restrict__ xoutf) {
  __shared__ alignas(16) ushort hT[64 * D];  // 64 KB
  const int tid = threadIdx.x;
  const int wave = tid >> 6;
  const int lane = tid & 63;
  const int node0 = blockIdx.x * 64;

  // ---------------- Phase A: aggregate into hT ----------------
  const float sc = 1.0f + eps_arr[layer];
  const size_t off = (size_t)lane * 8;
#pragma unroll 1
  for (int i = 0; i < 8; ++i) {
    const int nr = wave * 8 + i;
    const int node = node0 + nr;
    const uint4 u = *(const uint4*)(xin + (size_t)node * D + off);
    float a[8];
    a[0] = b_lo(u.x) * sc; a[1] = b_hi(u.x) * sc;
    a[2] = b_lo(u.y) * sc; a[3] = b_hi(u.y) * sc;
    a[4] = b_lo(u.z) * sc; a[5] = b_hi(u.z) * sc;
    a[6] = b_lo(u.w) * sc; a[7] = b_hi(u.w) * sc;
    int e = rowptr[node];
    const int en = rowptr[node + 1];
    for (; e + 4 <= en; e += 4) {
      const int s0 = csr[e], s1 = csr[e + 1], s2 = csr[e + 2], s3 = csr[e + 3];
      const uint4 v0 = *(const uint4*)(xin + (size_t)s0 * D + off);
      const uint4 v1 = *(const uint4*)(xin + (size_t)s1 * D + off);
      const uint4 v2 = *(const uint4*)(xin + (size_t)s2 * D + off);
      const uint4 v3 = *(const uint4*)(xin + (size_t)s3 * D + off);
      ACC8(v0); ACC8(v1); ACC8(v2); ACC8(v3);
    }
    if (e + 2 <= en) {
      const int s0 = csr[e], s1 = csr[e + 1];
      const uint4 v0 = *(const uint4*)(xin + (size_t)s0 * D + off);
      const uint4 v1 = *(const uint4*)(xin + (size_t)s1 * D + off);
      ACC8(v0); ACC8(v1);
      e += 2;
    }
    if (e < en) {
      const uint4 v0 = *(const uint4*)(xin + (size_t)csr[e] * D + off);
      ACC8(v0);
    }
    uint4 o;
    o.x = f2b(a[0]) | ((uint)f2b(a[1]) << 16);
    o.y = f2b(a[2]) | ((uint)f2b(a[3]) << 16);
    o.z = f2b(a[4]) | ((uint)f2b(a[5]) << 16);
    o.w = f2b(a[6]) | ((uint)f2b(a[7]) << 16);
    const int c = (lane & 56) | ((lane & 7) ^ (nr & 7));  // swizzled chunk
    *(uint4*)&hT[nr * D + c * 8] = o;
  }
  __syncthreads();

  // fragment addressing (shared by B and C)
  const int rsel = lane & 15;
  const int g = lane >> 4;
  const int key = rsel & 7;
  f32x4 acc[4][4];

#define MLP_GEMM(WT)                                                          \
  {                                                                           \
    _Pragma("unroll") for (int i_ = 0; i_ < 4; ++i_)                          \
        _Pragma("unroll") for (int j_ = 0; j_ < 4; ++j_)                      \
            acc[i_][j_] = (f32x4){0.f, 0.f, 0.f, 0.f};                        \
    _Pragma("unroll 1") for (int kt = 0; kt < 8; ++kt) {                      \
      _Pragma("unroll") for (int kk = 0; kk < 2; ++kk) {                      \
        const int cg = kk * 4 + g;                                            \
        const int ch = kt * 8 + (cg ^ key);                                   \
        bf16x8 af[4], bfr[4];                                                 \
        _Pragma("unroll") for (int j_ = 0; j_ < 4; ++j_)                      \
            bfr[j_] = *(const bf16x8*)&(WT)[(size_t)(wave * 64 + j_ * 16 + rsel) * D + \
                                            kt * 64 + cg * 8];                \
        _Pragma("unroll") for (int i_ = 0; i_ < 4; ++i_)                      \
            af[i_] = *(const bf16x8*)&hT[(i_ * 16 + rsel) * D + ch * 8];      \
        _Pragma("unroll") for (int i_ = 0; i_ < 4; ++i_)                      \
            _Pragma("unroll") for (int j_ = 0; j_ < 4; ++j_)                  \
                acc[i_][j_] = __builtin_amdgcn_mfma_f32_16x16x32_bf16(        \
                    af[i_], bfr[j_], acc[i_][j_], 0, 0, 0);                   \
      }                                                                       \
    }                                                                         \
  }

  // scatter leaky(acc+bias) into hT (C/D layout: col=lane&15, row=(lane>>4)*4+q)
#define MLP_SCATTER(BIAS)                                                     \
  {                                                                           \
    _Pragma("unroll") for (int i_ = 0; i_ < 4; ++i_)                          \
        _Pragma("unroll") for (int j_ = 0; j_ < 4; ++j_) {                    \
      const int col = wave * 64 + j_ * 16 + rsel;                             \
      const float bv = (BIAS)[col];                                           \
      const int chunk = col >> 3;                                             \
      _Pragma("unroll") for (int q_ = 0; q_ < 4; ++q_) {                      \
        const int row = i_ * 16 + g * 4 + q_;                                 \
        float v = acc[i_][j_][q_] + bv;                                       \
        v = (v > 0.f) ? v : 0.01f * v;                                        \
        const int swzc = (chunk & 56) | ((chunk & 7) ^ (row & 7));            \
        hT[row * D + swzc * 8 + (col & 7)] = f2b(v);                          \
      }                                                                       \
    }                                                                         \
  }

  // ---------------- Phase B: t = leaky(h @ W1 + b1) ----------------
  MLP_GEMM(W1T);
  __syncthreads();  // all waves done reading h
  MLP_SCATTER(b1);
  __syncthreads();  // t complete in hT

  // ---------------- Phase C: x' = leaky(t @ W2 + b2) ----------------
  MLP_GEMM(W2T);
  __syncthreads();  // all waves done reading t
  MLP_SCATTER(b2);
  __syncthreads();  // x' complete in hT
#undef MLP_GEMM
#undef MLP_SCATTER

  // ---------------- coalesced store: 64 rows x 1KB ----------------
#pragma unroll
  for (int it = 0; it < 8; ++it) {
    const int slot = it * 512 + tid;
    const int row = slot >> 6;
    const int chunk = slot & 63;
    const int swzc = (chunk & 56) | ((chunk & 7) ^ (row & 7));
    const uint4 v = *(const uint4*)&hT[row * D + swzc * 8];
    *(uint4*)(xoutb + (size_t)(node0 + row) * D + chunk * 8) = v;
    if (xoutf) {
      float4 f0, f1;
      f0.x = b_lo(v.x); f0.y = b_hi(v.x); f0.z = b_lo(v.y); f0.w = b_hi(v.y);
      f1.x = b_lo(v.z); f1.y = b_hi(v.z); f1.z = b_lo(v.w); f1.w = b_hi(v.w);
      float* op = xoutf + (size_t)(node0 + row) * D + chunk * 8;
      *(float4*)op = f0;
      *(float4*)(op + 4) = f1;
    }
  }
}

// ------------------------- segment max (pooling) ---------------------------
__global__ __launch_bounds__(256) void segmax_partial(const ushort* __restrict__ xb,
                                                      const int* __restrict__ gstart,
                                                      float* __restrict__ partial) {
  const int g = blockIdx.x, s = blockIdx.y, t = threadIdx.x;
  const int st = gstart[g], en = gstart[g + 1];
  const long long cnt = en - st;
  const int lo = st + (int)((cnt * s) >> 3);
  const int hi = st + (int)((cnt * (s + 1)) >> 3);
  float m0 = -3.4e38f, m1 = -3.4e38f;
  for (int n = lo; n < hi; ++n) {
    const uint u = *(const uint*)(xb + (size_t)n * D + t * 2);
    m0 = fmaxf(m0, b_lo(u));
    m1 = fmaxf(m1, b_hi(u));
  }
  float* p = partial + (size_t)(g * 8 + s) * D + t * 2;
  p[0] = m0;
  p[1] = m1;
}

__global__ void segmax_combine(const float* __restrict__ partial, float* __restrict__ maxval) {
  const int i = blockIdx.x * 256 + threadIdx.x;  // < B*D
  const int g = i >> 9, d0 = i & (D - 1);
  float m = partial[(size_t)(g * 8) * D + d0];
#pragma unroll
  for (int s = 1; s < 8; ++s) m = fmaxf(m, partial[(size_t)(g * 8 + s) * D + d0]);
  maxval[i] = m;
}

// -------- part (+)= maxval @ W + bias  (f32, W is [k][o] row-major) --------
__global__ __launch_bounds__(256) void pool_gemm(const float* __restrict__ maxval,
                                                 const float* __restrict__ Wp,
                                                 const float* __restrict__ bias,
                                                 float* __restrict__ part, int accumulate) {
  const int g = blockIdx.x;
  const int o = blockIdx.y * 256 + threadIdx.x;
  const float* mrow = maxval + (size_t)g * D;
  float acc = bias[o];
#pragma unroll 8
  for (int k = 0; k < D; ++k) acc = fmaf(mrow[k], Wp[(size_t)k * D + o], acc);
  const size_t idx = (size_t)g * D + o;
  part[idx] = accumulate ? part[idx] + acc : acc;
}

// ---------------------------------------------------------------------------
extern "C" void kernel_launch(void* const* d_in, const int* in_sizes, int n_in,
                              void* d_out, int out_size, void* d_ws, size_t ws_size,
                              hipStream_t stream) {
  const float* x = (const float*)d_in[0];
  const int* ei = (const int*)d_in[1];
  const int* batch = (const int*)d_in[2];
  const float* proj_w = (const float*)d_in[3];
  const float* proj_b = (const float*)d_in[4];
  const float* lin1_w = (const float*)d_in[5];
  const float* lin1_b = (const float*)d_in[6];
  const float* lin2_w = (const float*)d_in[7];
  const float* lin2_b = (const float*)d_in[8];
  const float* eps = (const float*)d_in[9];
  const float* pool_w = (const float*)d_in[10];
  const float* pool_b = (const float*)d_in[11];

  const int N = in_sizes[0] / D;  // 65536
  const int E = in_sizes[1] / 2;  // 524288
  const int B = 64;
  const int* src = ei;
  const int* dst = ei + E;

  float* part = (float*)d_out;         // [64][512]
  float* xout = part + (size_t)B * D;  // [N][512]

  // workspace carve
  char* w = (char*)d_ws;
  ushort* xb = (ushort*)w;   w += (size_t)N * D * 2;
  ushort* hb = (ushort*)w;   w += (size_t)N * D * 2;
  ushort* l1bt = (ushort*)w; w += (size_t)3 * D * D * 2;
  ushort* l2bt = (ushort*)w; w += (size_t)3 * D * D * 2;
  int* rowptr = (int*)w;     w += (size_t)(N + 4) * 4;
  int* cursor = (int*)w;     w += (size_t)N * 4;
  int* deg = (int*)w;        w += (size_t)N * 4;
  int* csr = (int*)w;        w += (size_t)E * 4;
  int* bsum = (int*)w;       w += 256 * 4;
  int* gstart = (int*)w;     w += 128 * 4;
  float* partial = (float*)w; w += (size_t)B * 8 * D * 4;
  float* maxval = (float*)w;  w += (size_t)B * D * 4;
  (void)ws_size; (void)n_in; (void)out_size;

  (void)hipMemsetAsync(deg, 0, (size_t)N * 4, stream);
  f32_to_bf16_vec<<<(N * (D / 8) + 255) / 256, 256, 0, stream>>>(x, xb, N * (D / 8));
  for (int l = 0; l < 3; ++l) {
    transpose_bf16<<<dim3(8, 8), 256, 0, stream>>>(lin1_w + (size_t)l * D * D,
                                                   l1bt + (size_t)l * D * D);
    transpose_bf16<<<dim3(8, 8), 256, 0, stream>>>(lin2_w + (size_t)l * D * D,
                                                   l2bt + (size_t)l * D * D);
  }
  count_deg<<<(E + 255) / 256, 256, 0, stream>>>(dst, deg, E);
  scan_block<<<N / 256, 256, 0, stream>>>(deg, rowptr, bsum);
  scan_block<<<1, 256, 0, stream>>>(bsum, bsum, (int*)nullptr);
  scan_fixup<<<N / 256, 256, 0, stream>>>(rowptr, bsum, cursor, N, E);
  fill_csr<<<(E + 255) / 256, 256, 0, stream>>>(src, dst, cursor, csr, E);
  compute_gstart<<<(N + 255) / 256, 256, 0, stream>>>(batch, gstart, N, B);

  // part = segmax(x) @ proj_w + proj_b
  segmax_partial<<<dim3(B, 8), 256, 0, stream>>>(xb, gstart, partial);
  segmax_combine<<<B * D / 256, 256, 0, stream>>>(partial, maxval);
  pool_gemm<<<dim3(B, 2), 256, 0, stream>>>(maxval, proj_w, proj_b, part, 0);

  // layers: ping-pong xb <-> hb; layer l reads cur, writes nxt
  ushort* cur = xb;
  ushort* nxt = hb;
  for (int l = 0; l < 3; ++l) {
    gin_layer<<<N / 64, 512, 0, stream>>>(
        cur, rowptr, csr, eps, l, l1bt + (size_t)l * D * D, lin1_b + (size_t)l * D,
        l2bt + (size_t)l * D * D, lin2_b + (size_t)l * D, nxt,
        (l == 2) ? xout : nullptr);
    segmax_partial<<<dim3(B, 8), 256, 0, stream>>>(nxt, gstart, partial);
    segmax_combine<<<B * D / 256, 256, 0, stream>>>(partial, maxval);
    pool_gemm<<<dim3(B, 2), 256, 0, stream>>>(maxval, pool_w + (size_t)l * D * D,
                                              pool_b + (size_t)l * D, part, 1);
    ushort* tmp = cur; cur = nxt; nxt = tmp;
  }
}

// Round 8
// 947.272 us; speedup vs baseline: 1.2233x; 1.2233x over previous
//
#include <hip/hip_runtime.h>

typedef unsigned int uint;
typedef unsigned short ushort;

#define D 512
#define GBM 256   // M-tile
#define GBN 256   // N-tile
#define GBK 64    // K-step

typedef __attribute__((ext_vector_type(8))) short bf16x8;
typedef __attribute__((ext_vector_type(4))) float f32x4;

__device__ __forceinline__ ushort f2b(float f) {
  uint u = __builtin_bit_cast(uint, f);
  return (ushort)((u + 0x7FFFu + ((u >> 16) & 1u)) >> 16);  // RNE
}
__device__ __forceinline__ float b_lo(uint u) { return __builtin_bit_cast(float, u << 16); }
__device__ __forceinline__ float b_hi(uint u) { return __builtin_bit_cast(float, u & 0xFFFF0000u); }

__device__ __forceinline__ void gload16(const void* g, void* l) {
  __builtin_amdgcn_global_load_lds((const __attribute__((address_space(1))) void*)g,
                                   (__attribute__((address_space(3))) void*)l, 16, 0, 0);
}

// ---------------- f32 -> bf16 bulk convert (8 elems/thread) ----------------
__global__ __launch_bounds__(256) void f32_to_bf16_vec(const float* __restrict__ in,
                                                       ushort* __restrict__ out, int n8) {
  const int i = blockIdx.x * 256 + threadIdx.x;
  if (i >= n8) return;
  const float4* p = (const float4*)in + (size_t)i * 2;
  float4 a = p[0], b = p[1];
  uint4 o;
  o.x = f2b(a.x) | ((uint)f2b(a.y) << 16);
  o.y = f2b(a.z) | ((uint)f2b(a.w) << 16);
  o.z = f2b(b.x) | ((uint)f2b(b.y) << 16);
  o.w = f2b(b.z) | ((uint)f2b(b.w) << 16);
  ((uint4*)out)[i] = o;
}

// ------------- transpose 512x512 f32 [k][o] -> bf16 BT [o][k] --------------
__global__ __launch_bounds__(256) void transpose_bf16(const float* __restrict__ W,
                                                      ushort* __restrict__ BT) {
  __shared__ float tile[64][65];
  const int bk = blockIdx.x * 64;  // k block
  const int bo = blockIdx.y * 64;  // o block
  const int tx = threadIdx.x & 63, ty = threadIdx.x >> 6;
#pragma unroll
  for (int r = 0; r < 64; r += 4)
    tile[r + ty][tx] = W[(size_t)(bk + r + ty) * D + bo + tx];
  __syncthreads();
#pragma unroll
  for (int r = 0; r < 64; r += 4)
    BT[(size_t)(bo + r + ty) * D + bk + tx] = f2b(tile[tx][r + ty]);
}

// ---------------------------- CSR build ------------------------------------
__global__ void count_deg(const int* __restrict__ dst, int* __restrict__ deg, int E) {
  const int e = blockIdx.x * 256 + threadIdx.x;
  if (e < E) atomicAdd(&deg[dst[e]], 1);
}

__global__ __launch_bounds__(256) void scan_block(const int* __restrict__ in,
                                                  int* __restrict__ out,
                                                  int* __restrict__ bsum) {
  __shared__ int sm[256];
  const int t = threadIdx.x;
  const int gi = blockIdx.x * 256 + t;
  const int v = in[gi];
  int x = v;
  sm[t] = x;
  __syncthreads();
#pragma unroll
  for (int off = 1; off < 256; off <<= 1) {
    const int y = (t >= off) ? sm[t - off] : 0;
    __syncthreads();
    x += y;
    sm[t] = x;
    __syncthreads();
  }
  out[gi] = x - v;  // exclusive
  if (t == 255 && bsum) bsum[blockIdx.x] = x;
}

__global__ void scan_fixup(int* __restrict__ rowptr, const int* __restrict__ bsum,
                           int* __restrict__ cursor, int N, int E) {
  const int i = blockIdx.x * 256 + threadIdx.x;
  const int r = rowptr[i] + bsum[i >> 8];
  rowptr[i] = r;
  cursor[i] = r;
  if (i == 0) rowptr[N] = E;
}

__global__ void fill_csr(const int* __restrict__ src, const int* __restrict__ dst,
                         int* __restrict__ cursor, int* __restrict__ csr, int E) {
  const int e = blockIdx.x * 256 + threadIdx.x;
  if (e >= E) return;
  const int pos = atomicAdd(&cursor[dst[e]], 1);
  csr[pos] = src[e];
}

// ------------------- graph start offsets (batch is sorted) -----------------
__global__ void compute_gstart(const int* __restrict__ batch, int* __restrict__ gstart,
                               int N, int B) {
  const int n = blockIdx.x * 256 + threadIdx.x;
  if (n >= N) return;
  const int b = batch[n];
  const int bp = (n == 0) ? -1 : batch[n - 1];
  for (int x = bp + 1; x <= b; ++x) gstart[x] = n;
  if (n == N - 1)
    for (int x = b + 1; x <= B; ++x) gstart[x] = N;
}

// --------------- GIN aggregation: h = (1+eps)*x + sum_nbr x ----------------
// One wave per node. Bounded by per-CU outstanding-miss capacity x latency on
// the random row gather (~3.8 TB/s fetch); at its structural floor
// (R2/R4 A/B: unroll neutral; R7 fusion: regression). Do not touch.
#define ACC8(v)                                          \
  a[0] += b_lo((v).x); a[1] += b_hi((v).x);              \
  a[2] += b_lo((v).y); a[3] += b_hi((v).y);              \
  a[4] += b_lo((v).z); a[5] += b_hi((v).z);              \
  a[6] += b_lo((v).w); a[7] += b_hi((v).w)

__global__ __launch_bounds__(256) void agg_kernel(const ushort* __restrict__ xb,
                                                  const int* __restrict__ rowptr,
                                                  const int* __restrict__ csr,
                                                  const float* __restrict__ eps_arr,
                                                  int layer, ushort* __restrict__ h) {
  const int node = blockIdx.x * 4 + (threadIdx.x >> 6);
  const int lane = threadIdx.x & 63;
  const float sc = 1.0f + eps_arr[layer];
  const size_t off = (size_t)lane * 8;
  const size_t base = (size_t)node * D + off;
  const uint4 u = *(const uint4*)(xb + base);
  float a[8];
  a[0] = b_lo(u.x) * sc; a[1] = b_hi(u.x) * sc;
  a[2] = b_lo(u.y) * sc; a[3] = b_hi(u.y) * sc;
  a[4] = b_lo(u.z) * sc; a[5] = b_hi(u.z) * sc;
  a[6] = b_lo(u.w) * sc; a[7] = b_hi(u.w) * sc;
  int e = rowptr[node];
  const int en = rowptr[node + 1];
  for (; e + 4 <= en; e += 4) {
    const int s0 = csr[e], s1 = csr[e + 1], s2 = csr[e + 2], s3 = csr[e + 3];
    const uint4 v0 = *(const uint4*)(xb + (size_t)s0 * D + off);
    const uint4 v1 = *(const uint4*)(xb + (size_t)s1 * D + off);
    const uint4 v2 = *(const uint4*)(xb + (size_t)s2 * D + off);
    const uint4 v3 = *(const uint4*)(xb + (size_t)s3 * D + off);
    ACC8(v0); ACC8(v1); ACC8(v2); ACC8(v3);
  }
  if (e + 2 <= en) {
    const int s0 = csr[e], s1 = csr[e + 1];
    const uint4 v0 = *(const uint4*)(xb + (size_t)s0 * D + off);
    const uint4 v1 = *(const uint4*)(xb + (size_t)s1 * D + off);
    ACC8(v0); ACC8(v1);
    e += 2;
  }
  if (e < en) {
    const uint4 v0 = *(const uint4*)(xb + (size_t)csr[e] * D + off);
    ACC8(v0);
  }
  uint4 o;
  o.x = f2b(a[0]) | ((uint)f2b(a[1]) << 16);
  o.y = f2b(a[2]) | ((uint)f2b(a[3]) << 16);
  o.z = f2b(a[4]) | ((uint)f2b(a[5]) << 16);
  o.w = f2b(a[6]) | ((uint)f2b(a[7]) << 16);
  *(uint4*)(h + base) = o;
}

// --------- bf16 GEMM: O = leaky(A @ BT^T + bias), 256x256 tile, BK=64 ------
// A [M][512] bf16 row-major, BT [512][512] bf16 with BT[o][k] = W[k][o].
// 8 waves (2 wave-rows x 4 wave-cols), per-wave output 128x64.
// 2-phase double buffer (m230-V0 structure, ~680 TF refcheck'd at 256²):
// STAGE(next K-tile -> other buffer) before COMPUTE(current).
// LDS 128 KB = 2 x (A 256x64 + B 256x64) bf16; epilogue C-tile reuses it.
// Chunk-XOR swizzle (rule 21, both sides): LDS[row][chunk] holds global
// chunk chunk^(row&7); staged via permuted GLOBAL source (linear gload_lds
// dest), read back with the same XOR.
__global__ __launch_bounds__(512, 1) void gemm_bias_leaky(
    const ushort* __restrict__ A, const ushort* __restrict__ BT,
    const float* __restrict__ bias, ushort* __restrict__ Obf,
    float* __restrict__ Of32) {
  __shared__ alignas(16) ushort smem[4 * GBM * GBK];  // 128 KB: A0,B0,A1,B1
  ushort* const lA0 = smem;
  ushort* const lB0 = smem + GBM * GBK;
  ushort* const lA1 = smem + 2 * GBM * GBK;
  ushort* const lB1 = smem + 3 * GBM * GBK;

  const int tid = threadIdx.x;
  const int lane = tid & 63;
  const int wave = tid >> 6;
  const int wr = wave >> 2, wc = wave & 3;  // 2x4 waves; 128x64 out each

  // XCD swizzle (nwg = 2*256 = 512, divisible by 8 -> bijective):
  const int lin = blockIdx.y * gridDim.x + blockIdx.x;
  const int nwg = gridDim.x * gridDim.y;
  const int wg = (lin & 7) * (nwg >> 3) + (lin >> 3);
  const int n0 = (wg & 1) * GBN;
  const size_t m0 = (size_t)(wg >> 1) * GBM;

  // staging: issue i covers rows [i*64, i*64+64); thread tid -> linear LDS
  // 16B slot (i*512+tid); row%8 and source chunk invariant across i.
  const int srow0 = tid >> 3;                        // 0..63
  const int schunk = ((tid & 7) ^ (srow0 & 7)) * 8;  // swizzled global chunk

  f32x4 acc[8][4] = {};

  // fragment-read addressing
  const int rsel = lane & 15;
  const int g = lane >> 4;
  const int key = rsel & 7;

#define STAGE(bufA, bufB, kt)                                                     \
  {                                                                               \
    const int k0_ = (kt) * GBK;                                                   \
    _Pragma("unroll") for (int i_ = 0; i_ < 4; ++i_) {                            \
      const int row_ = i_ * 64 + srow0;                                           \
      gload16(A + (m0 + row_) * D + k0_ + schunk, &(bufA)[(i_ * 512 + wave * 64) * 8]); \
      gload16(BT + (size_t)(n0 + row_) * D + k0_ + schunk,                        \
              &(bufB)[(i_ * 512 + wave * 64) * 8]);                               \
    }                                                                             \
  }

#define COMPUTE(bufA, bufB)                                                       \
  {                                                                               \
    _Pragma("unroll") for (int kk_ = 0; kk_ < 2; ++kk_) {                         \
      const int ch_ = ((kk_ * 4 + g) ^ key) * 8;                                  \
      bf16x8 af_[8], bf_[4];                                                      \
      _Pragma("unroll") for (int j_ = 0; j_ < 4; ++j_)                            \
          bf_[j_] = *(const bf16x8*)&(bufB)[(wc * 64 + j_ * 16 + rsel) * GBK + ch_]; \
      _Pragma("unroll") for (int i_ = 0; i_ < 8; ++i_)                            \
          af_[i_] = *(const bf16x8*)&(bufA)[(wr * 128 + i_ * 16 + rsel) * GBK + ch_]; \
      _Pragma("unroll") for (int i_ = 0; i_ < 8; ++i_)                            \
          _Pragma("unroll") for (int j_ = 0; j_ < 4; ++j_)                        \
              acc[i_][j_] = __builtin_amdgcn_mfma_f32_16x16x32_bf16(              \
                  af_[i_], bf_[j_], acc[i_][j_], 0, 0, 0);                        \
    }                                                                             \
  }

  // prologue: tile 0 -> buf0; then 2-phase pairs (K=512 -> 8 K-tiles)
  STAGE(lA0, lB0, 0);
  __syncthreads();
#pragma unroll
  for (int ktp = 0; ktp < 4; ++ktp) {
    STAGE(lA1, lB1, 2 * ktp + 1);
    COMPUTE(lA0, lB0);
    __syncthreads();
    if (ktp < 3) STAGE(lA0, lB0, 2 * ktp + 2);
    COMPUTE(lA1, lB1);
    __syncthreads();
  }
#undef STAGE
#undef COMPUTE

  // ---- epilogue: bias + leaky into LDS C-tile [256][256] bf16 (128 KB) ----
  // C/D layout: col=lane&15, row=(lane>>4)*4+reg (m89-verified)
#pragma unroll
  for (int j = 0; j < 4; ++j) {
    const int col = wc * 64 + j * 16 + rsel;
    const float bv = bias[n0 + col];
#pragma unroll
    for (int i = 0; i < 8; ++i) {
#pragma unroll
      for (int q = 0; q < 4; ++q) {
        const int row = wr * 128 + i * 16 + g * 4 + q;
        float v = acc[i][j][q] + bv;
        v = (v > 0.f) ? v : 0.01f * v;
        smem[row * GBN + col] = f2b(v);
      }
    }
  }
  __syncthreads();

  // ---- coalesced store: 32 chunks x 16B = 512B contiguous per row ----
#pragma unroll
  for (int it = 0; it < 16; ++it) {
    const int slot = it * 512 + tid;   // 8192 slots
    const int row = slot >> 5;
    const int chunk = slot & 31;
    const uint4 vv = *(const uint4*)&smem[row * GBN + chunk * 8];
    *(uint4*)(Obf + (m0 + row) * D + n0 + chunk * 8) = vv;
    if (Of32) {
      float4 f0, f1;
      f0.x = b_lo(vv.x); f0.y = b_hi(vv.x); f0.z = b_lo(vv.y); f0.w = b_hi(vv.y);
      f1.x = b_lo(vv.z); f1.y = b_hi(vv.z); f1.z = b_lo(vv.w); f1.w = b_hi(vv.w);
      float* op = Of32 + (m0 + row) * D + n0 + chunk * 8;
      *(float4*)op = f0;
      *(float4*)(op + 4) = f1;
    }
  }
}

// ------------------------- segment max (pooling) ---------------------------
__global__ __launch_bounds__(256) void segmax_partial(const ushort* __restrict__ xb,
                                                      const int* __restrict__ gstart,
                                                      float* __restrict__ partial) {
  const int g = blockIdx.x, s = blockIdx.y, t = threadIdx.x;
  const int st = gstart[g], en = gstart[g + 1];
  const long long cnt = en - st;
  const int lo = st + (int)((cnt * s) >> 3);
  const int hi = st + (int)((cnt * (s + 1)) >> 3);
  float m0 = -3.4e38f, m1 = -3.4e38f;
  for (int n = lo; n < hi; ++n) {
    const uint u = *(const uint*)(xb + (size_t)n * D + t * 2);
    m0 = fmaxf(m0, b_lo(u));
    m1 = fmaxf(m1, b_hi(u));
  }
  float* p = partial + (size_t)(g * 8 + s) * D + t * 2;
  p[0] = m0;
  p[1] = m1;
}

__global__ void segmax_combine(const float* __restrict__ partial, float* __restrict__ maxval) {
  const int i = blockIdx.x * 256 + threadIdx.x;  // < B*D
  const int g = i >> 9, d0 = i & (D - 1);
  float m = partial[(size_t)(g * 8) * D + d0];
#pragma unroll
  for (int s = 1; s < 8; ++s) m = fmaxf(m, partial[(size_t)(g * 8 + s) * D + d0]);
  maxval[i] = m;
}

// -------- part (+)= maxval @ W + bias  (f32, W is [k][o] row-major) --------
__global__ __launch_bounds__(256) void pool_gemm(const float* __restrict__ maxval,
                                                 const float* __restrict__ Wp,
                                                 const float* __restrict__ bias,
                                                 float* __restrict__ part, int accumulate) {
  const int g = blockIdx.x;
  const int o = blockIdx.y * 256 + threadIdx.x;
  const float* mrow = maxval + (size_t)g * D;
  float acc = bias[o];
#pragma unroll 8
  for (int k = 0; k < D; ++k) acc = fmaf(mrow[k], Wp[(size_t)k * D + o], acc);
  const size_t idx = (size_t)g * D + o;
  part[idx] = accumulate ? part[idx] + acc : acc;
}

// ---------------------------------------------------------------------------
extern "C" void kernel_launch(void* const* d_in, const int* in_sizes, int n_in,
                              void* d_out, int out_size, void* d_ws, size_t ws_size,
                              hipStream_t stream) {
  const float* x = (const float*)d_in[0];
  const int* ei = (const int*)d_in[1];
  const int* batch = (const int*)d_in[2];
  const float* proj_w = (const float*)d_in[3];
  const float* proj_b = (const float*)d_in[4];
  const float* lin1_w = (const float*)d_in[5];
  const float* lin1_b = (const float*)d_in[6];
  const float* lin2_w = (const float*)d_in[7];
  const float* lin2_b = (const float*)d_in[8];
  const float* eps = (const float*)d_in[9];
  const float* pool_w = (const float*)d_in[10];
  const float* pool_b = (const float*)d_in[11];

  const int N = in_sizes[0] / D;  // 65536
  const int E = in_sizes[1] / 2;  // 524288
  const int B = 64;
  const int* src = ei;
  const int* dst = ei + E;

  float* part = (float*)d_out;         // [64][512]
  float* xout = part + (size_t)B * D;  // [N][512]

  // workspace carve (~209 MB)
  char* w = (char*)d_ws;
  ushort* xb = (ushort*)w;   w += (size_t)N * D * 2;
  ushort* hb = (ushort*)w;   w += (size_t)N * D * 2;
  ushort* tb = (ushort*)w;   w += (size_t)N * D * 2;
  ushort* l1bt = (ushort*)w; w += (size_t)3 * D * D * 2;
  ushort* l2bt = (ushort*)w; w += (size_t)3 * D * D * 2;
  int* rowptr = (int*)w;     w += (size_t)(N + 4) * 4;
  int* cursor = (int*)w;     w += (size_t)N * 4;
  int* deg = (int*)w;        w += (size_t)N * 4;
  int* csr = (int*)w;        w += (size_t)E * 4;
  int* bsum = (int*)w;       w += 256 * 4;
  int* gstart = (int*)w;     w += 128 * 4;
  float* partial = (float*)w; w += (size_t)B * 8 * D * 4;
  float* maxval = (float*)w;  w += (size_t)B * D * 4;
  (void)ws_size; (void)n_in; (void)out_size;

  (void)hipMemsetAsync(deg, 0, (size_t)N * 4, stream);
  f32_to_bf16_vec<<<(N * (D / 8) + 255) / 256, 256, 0, stream>>>(x, xb, N * (D / 8));
  for (int l = 0; l < 3; ++l) {
    transpose_bf16<<<dim3(8, 8), 256, 0, stream>>>(lin1_w + (size_t)l * D * D,
                                                   l1bt + (size_t)l * D * D);
    transpose_bf16<<<dim3(8, 8), 256, 0, stream>>>(lin2_w + (size_t)l * D * D,
                                                   l2bt + (size_t)l * D * D);
  }
  count_deg<<<(E + 255) / 256, 256, 0, stream>>>(dst, deg, E);
  scan_block<<<N / 256, 256, 0, stream>>>(deg, rowptr, bsum);
  scan_block<<<1, 256, 0, stream>>>(bsum, bsum, (int*)nullptr);
  scan_fixup<<<N / 256, 256, 0, stream>>>(rowptr, bsum, cursor, N, E);
  fill_csr<<<(E + 255) / 256, 256, 0, stream>>>(src, dst, cursor, csr, E);
  compute_gstart<<<(N + 255) / 256, 256, 0, stream>>>(batch, gstart, N, B);

  // part = segmax(x) @ proj_w + proj_b
  segmax_partial<<<dim3(B, 8), 256, 0, stream>>>(xb, gstart, partial);
  segmax_combine<<<B * D / 256, 256, 0, stream>>>(partial, maxval);
  pool_gemm<<<dim3(B, 2), 256, 0, stream>>>(maxval, proj_w, proj_b, part, 0);

  for (int l = 0; l < 3; ++l) {
    agg_kernel<<<N / 4, 256, 0, stream>>>(xb, rowptr, csr, eps, l, hb);
    gemm_bias_leaky<<<dim3(D / GBN, N / GBM), 512, 0, stream>>>(
        hb, l1bt + (size_t)l * D * D, lin1_b + (size_t)l * D, tb, nullptr);
    gemm_bias_leaky<<<dim3(D / GBN, N / GBM), 512, 0, stream>>>(
        tb, l2bt + (size_t)l * D * D, lin2_b + (size_t)l * D, xb,
        (l == 2) ? xout : nullptr);
    segmax_partial<<<dim3(B, 8), 256, 0, stream>>>(xb, gstart, partial);
    segmax_combine<<<B * D / 256, 256, 0, stream>>>(partial, maxval);
    pool_gemm<<<dim3(B, 2), 256, 0, stream>>>(maxval, pool_w + (size_t)l * D * D,
                                              pool_b + (size_t)l * D, part, 1);
  }
}